// Round 1
// baseline (87.954 us; speedup 1.0000x reference)
//
#include <hip/hip_runtime.h>
#include <hip/hip_bf16.h>

// out[b, i*32+j, p*32+q] = sum_{s,t} (F^A_st enc[b,i])[p] * (F^B_st enc[b,j])[q]
// F^A_st = W_A X_msb^t P_s C_A N1_A ;  F^B_st = W_B Q_t C_B X_msb^s N1_B
// Wire w maps: wires 0..4 -> bits 4..0 of p (wire0 = MSB), wires 5..9 -> bits 4..0 of q.

__device__ __forceinline__ float2 cmulf(float2 a, float2 b) {
    return make_float2(a.x * b.x - a.y * b.y, a.x * b.y + a.y * b.x);
}
__device__ __forceinline__ float2 caddf(float2 a, float2 b) {
    return make_float2(a.x + b.x, a.y + b.y);
}

// ---------------- Kernel 1: enc = normalize(x @ W^T + b) ----------------
// grid 128 (one block per (b,t) row), block 256
__global__ __launch_bounds__(256) void enc_kernel(const float* __restrict__ x,
                                                  const float* __restrict__ W,
                                                  const float* __restrict__ bt,
                                                  float* __restrict__ enc) {
    int row = blockIdx.x;          // 0..127  (b*32 + t)
    int tid = threadIdx.x;
    int col = tid & 31;            // output column 0..31
    int seg = tid >> 5;            // 0..7, 64-element chunk of K=512
    const float* xs = x + (size_t)row * 512 + seg * 64;
    const float* ws = W + (size_t)col * 512 + seg * 64;
    float p = 0.f;
#pragma unroll
    for (int k = 0; k < 64; ++k) p += xs[k] * ws[k];
    __shared__ float part[8][32];
    part[seg][col] = p;
    __syncthreads();
    if (tid < 32) {
        float sum = bt[col];
#pragma unroll
        for (int g = 0; g < 8; ++g) sum += part[g][col];
        float sq = sum * sum;
        // reduce across lanes 0..31 (all within wave 0)
#pragma unroll
        for (int off = 1; off < 32; off <<= 1) sq += __shfl_xor(sq, off, 64);
        enc[row * 32 + col] = sum * (1.0f / sqrtf(sq));
    }
}

// ---------------- Kernel 2: build the 8 F matrices (32x32 complex) ----------------
// 1 block of 256 threads: thread = side(2) x s(2) x t(2) x column k(32)
__global__ __launch_bounds__(256) void build_F(const float* __restrict__ rx0,
                                               const float* __restrict__ ry0,
                                               const float* __restrict__ ry1,
                                               float2* __restrict__ F) {
    int tid = threadIdx.x;
    int side = tid >> 7;          // 0 = A (wires 0..4), 1 = B (wires 5..9)
    int s = (tid >> 6) & 1;
    int t = (tid >> 5) & 1;
    int k = tid & 31;

    float2 v[32];
#pragma unroll
    for (int m = 0; m < 32; ++m) v[m] = make_float2(m == k ? 1.f : 0.f, 0.f);

    int wbase = side * 5;
    // layer 1: G = RY(ry0) * RX(rx0) on each wire; wire (wbase+l) -> bit (4-l)
#pragma unroll
    for (int l = 0; l < 5; ++l) {
        float tx = rx0[wbase + l] * 0.5f, ty = ry0[wbase + l] * 0.5f;
        float cx = cosf(tx), sx = sinf(tx), cy = cosf(ty), sy = sinf(ty);
        float2 g00 = make_float2(cy * cx,  sy * sx);
        float2 g01 = make_float2(-sy * cx, -cy * sx);
        float2 g10 = make_float2(sy * cx,  -cy * sx);
        float2 g11 = make_float2(cy * cx,  -sy * sx);
        int bit = 1 << (4 - l);
#pragma unroll
        for (int m = 0; m < 32; ++m) {
            if (m & bit) continue;
            float2 a = v[m], b = v[m | bit];
            v[m]       = caddf(cmulf(g00, a), cmulf(g01, b));
            v[m | bit] = caddf(cmulf(g10, a), cmulf(g11, b));
        }
    }

    if (side == 0) {
        // C_A = C34 C23 C12 C01 (applied in circuit order)
#pragma unroll
        for (int l = 0; l < 4; ++l) {
            int cb = 1 << (4 - l), tb = 1 << (3 - l);
#pragma unroll
            for (int m = 0; m < 32; ++m) {
                if ((m & cb) && !(m & tb)) {
                    float2 tmp = v[m]; v[m] = v[m | tb]; v[m | tb] = tmp;
                }
            }
        }
        // P_s : keep LSB(p) == s (wire 4)
#pragma unroll
        for (int m = 0; m < 32; ++m)
            if ((m & 1) != s) v[m] = make_float2(0.f, 0.f);
        // X_msb^t (from CNOT(9,0) target on wire 0)
        if (t) {
#pragma unroll
            for (int m = 0; m < 16; ++m) {
                float2 tmp = v[m]; v[m] = v[m | 16]; v[m | 16] = tmp;
            }
        }
    } else {
        // X_msb^s (from CNOT(4,5) target on wire 5)
        if (s) {
#pragma unroll
            for (int m = 0; m < 16; ++m) {
                float2 tmp = v[m]; v[m] = v[m | 16]; v[m | 16] = tmp;
            }
        }
        // C_B = C89 C78 C67 C56
#pragma unroll
        for (int l = 0; l < 4; ++l) {
            int cb = 1 << (4 - l), tb = 1 << (3 - l);
#pragma unroll
            for (int m = 0; m < 32; ++m) {
                if ((m & cb) && !(m & tb)) {
                    float2 tmp = v[m]; v[m] = v[m | tb]; v[m | tb] = tmp;
                }
            }
        }
        // Q_t : keep LSB(q) == t (wire 9)
#pragma unroll
        for (int m = 0; m < 32; ++m)
            if ((m & 1) != t) v[m] = make_float2(0.f, 0.f);
    }

    // layer 2: RY(ry1) on each wire
#pragma unroll
    for (int l = 0; l < 5; ++l) {
        float ty = ry1[wbase + l] * 0.5f;
        float cy = cosf(ty), sy = sinf(ty);
        int bit = 1 << (4 - l);
#pragma unroll
        for (int m = 0; m < 32; ++m) {
            if (m & bit) continue;
            float2 a = v[m], b = v[m | bit];
            v[m]       = make_float2(cy * a.x - sy * b.x, cy * a.y - sy * b.y);
            v[m | bit] = make_float2(sy * a.x + cy * b.x, sy * a.y + cy * b.y);
        }
    }

    float2* dst = F + (size_t)(side * 4 + s * 2 + t) * 32 * 32;
#pragma unroll
    for (int p = 0; p < 32; ++p) dst[p * 32 + k] = v[p];
}

// ---------------- Kernel 3: U/V tables = F (complex 32x32) @ enc (real 32) ----------------
// grid 128 (one block per enc row), block 256: side(2) x st(4) x p(32)
__global__ __launch_bounds__(256) void matvec_uv(const float2* __restrict__ F,
                                                 const float* __restrict__ enc,
                                                 float2* __restrict__ U,
                                                 float2* __restrict__ V) {
    int row = blockIdx.x;
    int tid = threadIdx.x;
    int side = tid >> 7;
    int st = (tid >> 5) & 3;
    int p = tid & 31;
    __shared__ float e[32];
    if (tid < 32) e[tid] = enc[row * 32 + tid];
    __syncthreads();
    const float2* Fr = F + ((size_t)(side * 4 + st) * 32 + p) * 32;
    float2 acc = make_float2(0.f, 0.f);
#pragma unroll
    for (int k = 0; k < 32; ++k) {
        float ev = e[k];
        acc.x += Fr[k].x * ev;
        acc.y += Fr[k].y * ev;
    }
    float2* dst = (side == 0) ? U : V;
    dst[(size_t)row * 128 + st * 32 + p] = acc;
}

// ---------------- Kernel 4: out = sum of 4 complex outer products ----------------
// grid (1024, 4): bx = i*32+j, by = b ; block 256 ; each thread 4 outputs
__global__ __launch_bounds__(256) void outer_kernel(const float2* __restrict__ U,
                                                    const float2* __restrict__ V,
                                                    float* __restrict__ out,
                                                    int complex_out) {
    int bx = blockIdx.x;
    int b = blockIdx.y;
    int i = bx >> 5, j = bx & 31;
    int tid = threadIdx.x;
    __shared__ float2 su[128];
    __shared__ float2 sv[128];
    if (tid < 128) su[tid] = U[(size_t)(b * 32 + i) * 128 + tid];
    else           sv[tid - 128] = V[(size_t)(b * 32 + j) * 128 + (tid - 128)];
    __syncthreads();

    int d0 = tid << 2;            // 4 consecutive outputs per thread
    int p = d0 >> 5;
    int q0 = d0 & 31;
    float2 up0 = su[p], up1 = su[32 + p], up2 = su[64 + p], up3 = su[96 + p];

    float2 acc[4];
#pragma unroll
    for (int e = 0; e < 4; ++e) {
        int q = q0 + e;
        float2 v0 = sv[q], v1 = sv[32 + q], v2 = sv[64 + q], v3 = sv[96 + q];
        float2 a;
        a.x = up0.x * v0.x - up0.y * v0.y + up1.x * v1.x - up1.y * v1.y
            + up2.x * v2.x - up2.y * v2.y + up3.x * v3.x - up3.y * v3.y;
        a.y = up0.x * v0.y + up0.y * v0.x + up1.x * v1.y + up1.y * v1.x
            + up2.x * v2.y + up2.y * v2.x + up3.x * v3.y + up3.y * v3.x;
        acc[e] = a;
    }

    size_t pair = (size_t)b * 1024 + bx;
    if (complex_out) {
        float4* o = (float4*)(out + (pair * 1024 + d0) * 2);
        o[0] = make_float4(acc[0].x, acc[0].y, acc[1].x, acc[1].y);
        o[1] = make_float4(acc[2].x, acc[2].y, acc[3].x, acc[3].y);
    } else {
        float4* o = (float4*)(out + pair * 1024 + d0);
        o[0] = make_float4(acc[0].x, acc[1].x, acc[2].x, acc[3].x);
    }
}

extern "C" void kernel_launch(void* const* d_in, const int* in_sizes, int n_in,
                              void* d_out, int out_size, void* d_ws, size_t ws_size,
                              hipStream_t stream) {
    const float* x   = (const float*)d_in[0];   // (4,32,512)
    const float* W   = (const float*)d_in[1];   // (32,512)
    const float* bt  = (const float*)d_in[2];   // (32,)
    const float* rx0 = (const float*)d_in[3];   // (10,)
    const float* ry0 = (const float*)d_in[4];   // (10,)
    const float* ry1 = (const float*)d_in[5];   // (10,)

    // workspace layout (float2 units):
    // F: 8 * 32 * 32 = 8192  | U: 128*128 = 16384 | V: 16384 | enc: 4096 floats
    float2* F = (float2*)d_ws;
    float2* U = F + 8192;
    float2* V = U + 16384;
    float*  enc = (float*)(V + 16384);

    enc_kernel<<<128, 256, 0, stream>>>(x, W, bt, enc);
    build_F<<<1, 256, 0, stream>>>(rx0, ry0, ry1, F);
    matvec_uv<<<128, 256, 0, stream>>>(F, enc, U, V);

    // complex64 output (4,1024,1024) -> 8388608 interleaved floats
    int complex_out = (out_size > 4 * 1024 * 1024) ? 1 : 0;
    dim3 grid(1024, 4);
    outer_kernel<<<grid, 256, 0, stream>>>(U, V, (float*)d_out, complex_out);
}

// Round 2
// 79.616 us; speedup vs baseline: 1.1047x; 1.1047x over previous
//
#include <hip/hip_runtime.h>
#include <hip/hip_bf16.h>

// out[b, i*32+j, p*32+q] = sum_{s,t} U_st[b,i][p] * V_st[b,j][q]
// where U/V are the enc vectors pushed through the factorized circuit:
//   U_st = W_A X_msb^t P_s C_A N1_A enc ;  V_st = W_B Q_t C_B X_msb^s N1_B enc
// Wires 0..4 -> bits 4..0 of p (wire0 = MSB), wires 5..9 -> bits 4..0 of q.

__device__ __forceinline__ float2 cmulf(float2 a, float2 b) {
    return make_float2(a.x * b.x - a.y * b.y, a.x * b.y + a.y * b.x);
}
__device__ __forceinline__ float2 caddf(float2 a, float2 b) {
    return make_float2(a.x + b.x, a.y + b.y);
}
__device__ __forceinline__ float2 shflx(float2 v, int mask) {
    return make_float2(__shfl_xor(v.x, mask, 64), __shfl_xor(v.y, mask, 64));
}

// ---------------- Kernel 1: enc + circuit transform, fused ----------------
// grid 128 (one block per (b,t) row), block 256.
// Phase 1: enc row = normalize(x_row @ W^T + b)  -> LDS e[32]
// Phase 2: thread = side(2) x s(2) x t(2) x p(32); each 32-lane group pushes
//          e[] through its circuit branch via shfl_xor butterflies.
__global__ __launch_bounds__(256) void prep_kernel(const float* __restrict__ x,
                                                   const float* __restrict__ W,
                                                   const float* __restrict__ bt,
                                                   const float* __restrict__ rx0,
                                                   const float* __restrict__ ry0,
                                                   const float* __restrict__ ry1,
                                                   float2* __restrict__ U,
                                                   float2* __restrict__ V) {
    int row = blockIdx.x;          // 0..127  (b*32 + t)
    int tid = threadIdx.x;
    int col = tid & 31;            // enc column 0..31
    int seg = tid >> 5;            // 0..7, 64-element chunk of K=512
    const float* xs = x + (size_t)row * 512 + seg * 64;
    const float* ws = W + (size_t)col * 512 + seg * 64;
    float part_acc = 0.f;
#pragma unroll
    for (int k = 0; k < 64; ++k) part_acc += xs[k] * ws[k];
    __shared__ float part[8][32];
    __shared__ float e[32];
    part[seg][col] = part_acc;
    __syncthreads();
    if (tid < 32) {
        float sum = bt[tid];
#pragma unroll
        for (int g = 0; g < 8; ++g) sum += part[g][tid];
        float sq = sum * sum;
#pragma unroll
        for (int off = 1; off < 32; off <<= 1) sq += __shfl_xor(sq, off, 64);
        e[tid] = sum * (1.0f / sqrtf(sq));
    }
    __syncthreads();

    // ---- phase 2: circuit on 32-dim complex vector, one element per lane ----
    int side = tid >> 7;           // 0 = A (wires 0..4 -> p), 1 = B (wires 5..9 -> q)
    int s = (tid >> 6) & 1;
    int t = (tid >> 5) & 1;
    int p = tid & 31;
    int wb = side * 5;

    float2 c = make_float2(e[p], 0.f);

    // layer 1: RY(ry0)*RX(rx0) butterfly per wire; wire (wb+l) -> bit (4-l)
#pragma unroll
    for (int l = 0; l < 5; ++l) {
        float tx = rx0[wb + l] * 0.5f, ty = ry0[wb + l] * 0.5f;
        float cx = cosf(tx), sx = sinf(tx), cy = cosf(ty), sy = sinf(ty);
        int bit = 1 << (4 - l);
        float2 pr = shflx(c, bit);
        float2 g00 = make_float2(cy * cx,  sy * sx);
        float2 g01 = make_float2(-sy * cx, -cy * sx);
        float2 g10 = make_float2(sy * cx,  -cy * sx);
        float2 g11 = make_float2(cy * cx,  -sy * sx);
        c = ((p & bit) == 0) ? caddf(cmulf(g00, c), cmulf(g01, pr))
                             : caddf(cmulf(g10, pr), cmulf(g11, c));
    }

    if (side == 0) {
        // C_A chain: C(0,1) C(1,2) C(2,3) C(3,4) in circuit order
#pragma unroll
        for (int l = 0; l < 4; ++l) {
            int cb = 1 << (4 - l), tb = 1 << (3 - l);
            float2 pr = shflx(c, tb);
            if (p & cb) c = pr;
        }
        // P_s: keep LSB(p) == s (wire 4 control of CNOT(4,5))
        if ((p & 1) != s) c = make_float2(0.f, 0.f);
        // X_msb^t (target of CNOT(9,0) on wire 0)
        { float2 pr = shflx(c, 16); if (t) c = pr; }
    } else {
        // X_msb^s (target of CNOT(4,5) on wire 5)
        { float2 pr = shflx(c, 16); if (s) c = pr; }
        // C_B chain: C(5,6) C(6,7) C(7,8) C(8,9)
#pragma unroll
        for (int l = 0; l < 4; ++l) {
            int cb = 1 << (4 - l), tb = 1 << (3 - l);
            float2 pr = shflx(c, tb);
            if (p & cb) c = pr;
        }
        // Q_t: keep LSB(q) == t (wire 9 control of CNOT(9,0))
        if ((p & 1) != t) c = make_float2(0.f, 0.f);
    }

    // layer 2: RY(ry1) butterfly per wire (real 2x2)
#pragma unroll
    for (int l = 0; l < 5; ++l) {
        float ty = ry1[wb + l] * 0.5f;
        float cy = cosf(ty), sy = sinf(ty);
        int bit = 1 << (4 - l);
        float2 pr = shflx(c, bit);
        c = ((p & bit) == 0)
              ? make_float2(cy * c.x - sy * pr.x, cy * c.y - sy * pr.y)
              : make_float2(sy * pr.x + cy * c.x, sy * pr.y + cy * c.y);
    }

    float2* dst = (side == 0) ? U : V;
    dst[(size_t)row * 128 + (s * 2 + t) * 32 + p] = c;
}

// ---------------- Kernel 2: out = sum of 4 complex outer products ----------------
// grid (1024, 4): bx = i*32+j, by = b ; block 256 ; each thread 4 outputs
__global__ __launch_bounds__(256) void outer_kernel(const float2* __restrict__ U,
                                                    const float2* __restrict__ V,
                                                    float* __restrict__ out,
                                                    int complex_out) {
    int bx = blockIdx.x;
    int b = blockIdx.y;
    int i = bx >> 5, j = bx & 31;
    int tid = threadIdx.x;
    __shared__ float2 su[128];
    __shared__ float2 sv[128];
    if (tid < 128) su[tid] = U[(size_t)(b * 32 + i) * 128 + tid];
    else           sv[tid - 128] = V[(size_t)(b * 32 + j) * 128 + (tid - 128)];
    __syncthreads();

    int d0 = tid << 2;            // 4 consecutive outputs per thread
    int p = d0 >> 5;
    int q0 = d0 & 31;
    float2 up0 = su[p], up1 = su[32 + p], up2 = su[64 + p], up3 = su[96 + p];

    float2 acc[4];
#pragma unroll
    for (int e = 0; e < 4; ++e) {
        int q = q0 + e;
        float2 v0 = sv[q], v1 = sv[32 + q], v2 = sv[64 + q], v3 = sv[96 + q];
        float2 a;
        a.x = up0.x * v0.x - up0.y * v0.y + up1.x * v1.x - up1.y * v1.y
            + up2.x * v2.x - up2.y * v2.y + up3.x * v3.x - up3.y * v3.y;
        a.y = up0.x * v0.y + up0.y * v0.x + up1.x * v1.y + up1.y * v1.x
            + up2.x * v2.y + up2.y * v2.x + up3.x * v3.y + up3.y * v3.x;
        acc[e] = a;
    }

    size_t pair = (size_t)b * 1024 + bx;
    if (complex_out) {
        float4* o = (float4*)(out + (pair * 1024 + d0) * 2);
        o[0] = make_float4(acc[0].x, acc[0].y, acc[1].x, acc[1].y);
        o[1] = make_float4(acc[2].x, acc[2].y, acc[3].x, acc[3].y);
    } else {
        float4* o = (float4*)(out + pair * 1024 + d0);
        o[0] = make_float4(acc[0].x, acc[1].x, acc[2].x, acc[3].x);
    }
}

extern "C" void kernel_launch(void* const* d_in, const int* in_sizes, int n_in,
                              void* d_out, int out_size, void* d_ws, size_t ws_size,
                              hipStream_t stream) {
    const float* x   = (const float*)d_in[0];   // (4,32,512)
    const float* W   = (const float*)d_in[1];   // (32,512)
    const float* bt  = (const float*)d_in[2];   // (32,)
    const float* rx0 = (const float*)d_in[3];   // (10,)
    const float* ry0 = (const float*)d_in[4];   // (10,)
    const float* ry1 = (const float*)d_in[5];   // (10,)

    // workspace layout (float2 units): U: 128*128 = 16384 | V: 16384
    float2* U = (float2*)d_ws;
    float2* V = U + 16384;

    prep_kernel<<<128, 256, 0, stream>>>(x, W, bt, rx0, ry0, ry1, U, V);

    // complex64 output (4,1024,1024) -> 8388608 interleaved floats
    int complex_out = (out_size > 4 * 1024 * 1024) ? 1 : 0;
    dim3 grid(1024, 4);
    outer_kernel<<<grid, 256, 0, stream>>>(U, V, (float*)d_out, complex_out);
}